// Round 12
// baseline (763.176 us; speedup 1.0000x reference)
//
#include <hip/hip_runtime.h>

// MultiAgentDRQN R12. R10/R11 established: the allocator caps these kernels at
// 128 VGPRs no matter the launch-bounds hint -> ~100 of gru3's 192 weight
// floats reload from L2 every step (Whh 49KB > 32KB L1). Stop fighting it:
// AMORTIZE. gru4_k: one wave serves TWO sequences -- each weight register
// read feeds 2 FMAs (seq A+B), halving reload overhead per unit work. Fused
// k-loop, hs[2][64], distance-2 gi prefetch per seq, single-acc chains.
// 1024 blocks x 64 thr (R11's 256-thr packing regressed; reverted).
// fc1_k (split-K) / gi_k unchanged. Fallback: R1 fused if ws too small.

namespace {
constexpr int kB = 256, kT = 200, kN = 8, kObs = 128, kH = 64, kOut = 16;
constexpr int kRows = kB * kT * kN;                  // 409600
constexpr size_t kABytes  = (size_t)kRows * 64 * 4;  // 100 MB
constexpr size_t kGiBytes = (size_t)kRows * 192 * 4; // 300 MB
}

// ------- fc1_k: a[r][64] = relu(x_r . W1^T + b1), split-K 2 waves/row --------
__global__ __launch_bounds__(256, 2)
void fc1_k(const float* __restrict__ obs, const int* __restrict__ agent,
           const float* __restrict__ W1, const float* __restrict__ b1,
           float* __restrict__ a_out) {
  __shared__ float xs[2][2][128];   // [engine][buf][k]
  __shared__ float ps[2][2][64];    // [engine][buf][out] partial sums
  __shared__ float ohs[512];        // ohs[n*64+l] = W1[l][128+agent[n]]
  const int tid = threadIdx.x, lane = tid & 63, w = tid >> 6;
  const int e = w >> 1, p = w & 1;  // engine, k-half

  for (int i = tid; i < 512; i += 256) {
    int n = i >> 6, l = i & 63;
    ohs[i] = W1[(size_t)l * 136 + 128 + agent[n]];
  }

  float4 wv[16];
  #pragma unroll
  for (int k = 0; k < 16; ++k)
    wv[k] = *(const float4*)(W1 + (size_t)lane * 136 + p * 64 + k * 4);
  const float b1r = b1[lane];       // used by finishing wave (p==1)

  constexpr int ROWS = 100;         // 4096 engines x 100 rows = 409600
  const int eng = blockIdx.x * 2 + e;
  const int r0 = eng * ROWS;
  const int et = p * 64 + lane;     // engine-local staging index [0,128)

  xs[e][0][et] = obs[(size_t)r0 * 128 + et];
  float xq = obs[(size_t)(r0 + 1) * 128 + et];
  __syncthreads();                  // covers ohs + row-0 staging

  #pragma unroll 1
  for (int i = 0; i < ROWS; ++i) {
    const int r = r0 + i;
    if (i + 1 < ROWS) xs[e][(i + 1) & 1][et] = xq;
    const int nr = (i + 2 < ROWS) ? (r0 + i + 2) : (r0 + ROWS - 1);
    xq = obs[(size_t)nr * 128 + et];

    const float* xb = xs[e][i & 1] + p * 64;
    float a0 = 0.f, a1 = 0.f, a2 = 0.f, a3 = 0.f;
    #pragma unroll
    for (int k = 0; k < 16; ++k) {
      float4 xp = *(const float4*)(xb + k * 4);   // same-addr broadcast read
      a0 = fmaf(wv[k].x, xp.x, a0);
      a1 = fmaf(wv[k].y, xp.y, a1);
      a2 = fmaf(wv[k].z, xp.z, a2);
      a3 = fmaf(wv[k].w, xp.w, a3);
    }
    const float part = (a0 + a1) + (a2 + a3);
    if (p == 0) ps[e][i & 1][lane] = part;
    __syncthreads();                // ps(i) visible; dbuf protects i+2 reuse
    if (p == 1) {
      float av = part + ps[e][i & 1][lane] + b1r + ohs[(r & 7) * 64 + lane];
      a_out[(size_t)r * 64 + lane] = fmaxf(av, 0.f);
    }
  }
}

// ---------------- gi_k: gi[r][192] = Wih . a_r + bih -------------------------
__global__ __launch_bounds__(256, 2)
void gi_k(const float* __restrict__ a_glob, const float* __restrict__ Wih,
          const float* __restrict__ bih, float* __restrict__ gi_out) {
  __shared__ float as_[4][2][64];
  const int tid = threadIdx.x, lane = tid & 63, w = tid >> 6;

  float wir[64], wiz[64], win_[64];
  #pragma unroll
  for (int k = 0; k < 64; k += 4) {
    *(float4*)&wir[k]  = *(const float4*)(Wih + (size_t)lane * 64 + k);
    *(float4*)&wiz[k]  = *(const float4*)(Wih + (size_t)(64 + lane) * 64 + k);
    *(float4*)&win_[k] = *(const float4*)(Wih + (size_t)(128 + lane) * 64 + k);
  }
  const float bir = bih[lane], biz = bih[64 + lane], bin_ = bih[128 + lane];

  const int gwave = blockIdx.x * 4 + w;   // 2048 waves x 200 rows
  const int r0 = gwave * 200;
  float (*ab)[64] = as_[w];

  ab[0][lane] = a_glob[(size_t)r0 * 64 + lane];
  float qA = a_glob[(size_t)(r0 + 1) * 64 + lane];
  float qB = a_glob[(size_t)(r0 + 2) * 64 + lane];

#define GI_BODY(T, Q, NEXT)                                                    \
  {                                                                            \
    const int t_ = (T);                                                        \
    if (t_ < 199) ab[(t_ + 1) & 1][lane] = Q;                                  \
    const int nr_ = (NEXT) > 199 ? 199 : (NEXT);                               \
    Q = a_glob[(size_t)(r0 + nr_) * 64 + lane];                                \
    const float* ap_ = ab[t_ & 1];                                             \
    float r0a = bir, r1a = 0.f, z0a = biz, z1a = 0.f, n0a = bin_, n1a = 0.f;   \
    _Pragma("unroll") for (int k = 0; k < 64; k += 4) {                        \
      float4 av = *(const float4*)(ap_ + k);                                   \
      r0a = fmaf(wir[k], av.x, r0a);  r1a = fmaf(wir[k + 1], av.y, r1a);       \
      r0a = fmaf(wir[k + 2], av.z, r0a); r1a = fmaf(wir[k + 3], av.w, r1a);    \
      z0a = fmaf(wiz[k], av.x, z0a);  z1a = fmaf(wiz[k + 1], av.y, z1a);       \
      z0a = fmaf(wiz[k + 2], av.z, z0a); z1a = fmaf(wiz[k + 3], av.w, z1a);    \
      n0a = fmaf(win_[k], av.x, n0a); n1a = fmaf(win_[k + 1], av.y, n1a);      \
      n0a = fmaf(win_[k + 2], av.z, n0a); n1a = fmaf(win_[k + 3], av.w, n1a);  \
    }                                                                          \
    float* gp_ = gi_out + (size_t)(r0 + t_) * 192;                             \
    gp_[lane] = r0a + r1a;                                                     \
    gp_[64 + lane] = z0a + z1a;                                                \
    gp_[128 + lane] = n0a + n1a;                                               \
  }

  #pragma unroll 1
  for (int i = 0; i < 200; i += 2) {
    GI_BODY(i + 0, qA, i + 3)
    GI_BODY(i + 1, qB, i + 4)
  }
#undef GI_BODY
}

// ---- gru4_k: 1 wave = 2 sequences; weights amortized across both ------------
__global__ __launch_bounds__(64, 1)
void gru4_k(const float* __restrict__ gi_glob,
            const float* __restrict__ Whh, const float* __restrict__ bhh,
            const float* __restrict__ W2, const float* __restrict__ b2,
            float* __restrict__ out) {
  __shared__ float hs[2][64];
  const int lane = threadIdx.x;
  float* hs0 = hs[0];
  float* hs1 = hs[1];

  float whr[64], whz[64], whn[64];
  #pragma unroll
  for (int k = 0; k < 64; k += 4) {
    *(float4*)&whr[k] = *(const float4*)(Whh + (size_t)lane * 64 + k);
    *(float4*)&whz[k] = *(const float4*)(Whh + (size_t)(64 + lane) * 64 + k);
    *(float4*)&whn[k] = *(const float4*)(Whh + (size_t)(128 + lane) * 64 + k);
  }
  const float bhr = bhh[lane], bhz = bhh[64 + lane], bhn = bhh[128 + lane];
  const int m = lane & 15, qt = lane >> 4;
  float w2r[16];
  #pragma unroll
  for (int j = 0; j < 16; j += 4)
    *(float4*)&w2r[j] = *(const float4*)(W2 + (size_t)m * 64 + qt * 16 + j);
  const float b2r = b2[m];

  const int sA = blockIdx.x * 2, sB = sA + 1;
  const size_t rbaseA = (size_t)(sA >> 3) * 1600 + (sA & 7);
  const size_t rbaseB = (size_t)(sB >> 3) * 1600 + (sB & 7);

  float* outq  = out;
  float* outmv = out + (size_t)kRows * 16;
  float* outma = outmv + kRows;

  hs0[lane] = 0.f; hs1[lane] = 0.f;
  float hA = 0.f, hB = 0.f;

  // prefetch gi: seq A slots (t=0 -> gA, t=1 -> gB), seq B (gC, gD)
  const float* pA0 = gi_glob + rbaseA * 192;
  float gA0 = pA0[lane], gA1 = pA0[64 + lane], gA2 = pA0[128 + lane];
  const float* pA1 = gi_glob + (rbaseA + 8) * 192;
  float gB0 = pA1[lane], gB1 = pA1[64 + lane], gB2 = pA1[128 + lane];
  const float* pB0 = gi_glob + rbaseB * 192;
  float gC0 = pB0[lane], gC1 = pB0[64 + lane], gC2 = pB0[128 + lane];
  const float* pB1 = gi_glob + (rbaseB + 8) * 192;
  float gD0 = pB1[lane], gD1 = pB1[64 + lane], gD2 = pB1[128 + lane];

#define GSTEP2(T, GA0_, GA1_, GA2_, GC0_, GC1_, GC2_, TN)                      \
  {                                                                            \
    const int t_ = (T);                                                        \
    const size_t rA_ = rbaseA + (size_t)t_ * 8;                                \
    const size_t rB_ = rbaseB + (size_t)t_ * 8;                                \
    float hrA = bhr, hzA = bhz, hnA = bhn;                                     \
    float hrB = bhr, hzB = bhz, hnB = bhn;                                     \
    _Pragma("unroll") for (int k = 0; k < 64; k += 4) {                        \
      float4 hpA = *(const float4*)(hs0 + k);                                  \
      float4 hpB = *(const float4*)(hs1 + k);                                  \
      hrA = fmaf(whr[k], hpA.x, hrA);   hrB = fmaf(whr[k], hpB.x, hrB);        \
      hrA = fmaf(whr[k+1], hpA.y, hrA); hrB = fmaf(whr[k+1], hpB.y, hrB);      \
      hrA = fmaf(whr[k+2], hpA.z, hrA); hrB = fmaf(whr[k+2], hpB.z, hrB);      \
      hrA = fmaf(whr[k+3], hpA.w, hrA); hrB = fmaf(whr[k+3], hpB.w, hrB);      \
      hzA = fmaf(whz[k], hpA.x, hzA);   hzB = fmaf(whz[k], hpB.x, hzB);        \
      hzA = fmaf(whz[k+1], hpA.y, hzA); hzB = fmaf(whz[k+1], hpB.y, hzB);      \
      hzA = fmaf(whz[k+2], hpA.z, hzA); hzB = fmaf(whz[k+2], hpB.z, hzB);      \
      hzA = fmaf(whz[k+3], hpA.w, hzA); hzB = fmaf(whz[k+3], hpB.w, hzB);      \
      hnA = fmaf(whn[k], hpA.x, hnA);   hnB = fmaf(whn[k], hpB.x, hnB);        \
      hnA = fmaf(whn[k+1], hpA.y, hnA); hnB = fmaf(whn[k+1], hpB.y, hnB);      \
      hnA = fmaf(whn[k+2], hpA.z, hnA); hnB = fmaf(whn[k+2], hpB.z, hnB);      \
      hnA = fmaf(whn[k+3], hpA.w, hnA); hnB = fmaf(whn[k+3], hpB.w, hnB);      \
    }                                                                          \
    const float rgA = 1.f / (1.f + __expf(-((GA0_) + hrA)));                   \
    const float zgA = 1.f / (1.f + __expf(-((GA1_) + hzA)));                   \
    const float eA = __expf(2.f * ((GA2_) + rgA * hnA));                       \
    hA = (1.f - zgA) * (1.f - 2.f / (eA + 1.f)) + zgA * hA;                    \
    hs0[lane] = hA;                                                            \
    const float rgB = 1.f / (1.f + __expf(-((GC0_) + hrB)));                   \
    const float zgB = 1.f / (1.f + __expf(-((GC1_) + hzB)));                   \
    const float eB = __expf(2.f * ((GC2_) + rgB * hnB));                       \
    hB = (1.f - zgB) * (1.f - 2.f / (eB + 1.f)) + zgB * hB;                    \
    hs1[lane] = hB;                                                            \
    const int tn_ = (TN) > 199 ? 199 : (TN);                                   \
    const float* qpA_ = gi_glob + (rbaseA + (size_t)tn_ * 8) * 192;            \
    GA0_ = qpA_[lane]; GA1_ = qpA_[64 + lane]; GA2_ = qpA_[128 + lane];        \
    const float* qpB_ = gi_glob + (rbaseB + (size_t)tn_ * 8) * 192;            \
    GC0_ = qpB_[lane]; GC1_ = qpB_[64 + lane]; GC2_ = qpB_[128 + lane];        \
    float qa0 = 0.f, qa1 = 0.f, qb0 = 0.f, qb1 = 0.f;                          \
    _Pragma("unroll") for (int j = 0; j < 16; j += 4) {                        \
      float4 ha_ = *(const float4*)(hs0 + qt * 16 + j);                        \
      float4 hb_ = *(const float4*)(hs1 + qt * 16 + j);                        \
      qa0 = fmaf(w2r[j], ha_.x, qa0);     qb0 = fmaf(w2r[j], hb_.x, qb0);      \
      qa1 = fmaf(w2r[j + 1], ha_.y, qa1); qb1 = fmaf(w2r[j + 1], hb_.y, qb1);  \
      qa0 = fmaf(w2r[j + 2], ha_.z, qa0); qb0 = fmaf(w2r[j + 2], hb_.z, qb0);  \
      qa1 = fmaf(w2r[j + 3], ha_.w, qa1); qb1 = fmaf(w2r[j + 3], hb_.w, qb1);  \
    }                                                                          \
    float qa = qa0 + qa1, qb = qb0 + qb1;                                      \
    qa += __shfl_xor(qa, 16); qa += __shfl_xor(qa, 32); qa += b2r;             \
    qb += __shfl_xor(qb, 16); qb += __shfl_xor(qb, 32); qb += b2r;             \
    if (lane < 16) {                                                           \
      outq[rA_ * 16 + m] = qa;                                                 \
      outq[rB_ * 16 + m] = qb;                                                 \
    }                                                                          \
    float bvA = qa; int biA = m;                                               \
    float bvB = qb; int biB = m;                                               \
    _Pragma("unroll") for (int d = 1; d < 16; d <<= 1) {                       \
      float ovA = __shfl_xor(bvA, d, 16); int oiA = __shfl_xor(biA, d, 16);    \
      if (ovA > bvA || (ovA == bvA && oiA < biA)) { bvA = ovA; biA = oiA; }    \
      float ovB = __shfl_xor(bvB, d, 16); int oiB = __shfl_xor(biB, d, 16);    \
      if (ovB > bvB || (ovB == bvB && oiB < biB)) { bvB = ovB; biB = oiB; }    \
    }                                                                          \
    if (lane == 0) {                                                           \
      outmv[rA_] = bvA; outma[rA_] = (float)biA;                               \
      outmv[rB_] = bvB; outma[rB_] = (float)biB;                               \
    }                                                                          \
  }

  #pragma unroll 1
  for (int t = 0; t < 200; t += 2) {
    GSTEP2(t,     gA0, gA1, gA2, gC0, gC1, gC2, t + 2)
    GSTEP2(t + 1, gB0, gB1, gB2, gD0, gD1, gD2, t + 3)
  }
#undef GSTEP2
}

// ---------------- R1 fallback (no/small workspace) ---------------------------
namespace fb {
constexpr int kW1Pitch = 137, kHPitch = 65;
constexpr int OFF_W1 = 0;
constexpr int OFF_WIH = OFF_W1 + 64 * kW1Pitch;
constexpr int OFF_WHH = OFF_WIH + 192 * kHPitch;
constexpr int OFF_W2 = OFF_WHH + 192 * kHPitch;
constexpr int OFF_B1 = OFF_W2 + 16 * kHPitch;
constexpr int OFF_BIH = OFF_B1 + 64;
constexpr int OFF_BHH = OFF_BIH + 192;
constexpr int OFF_B2 = OFF_BHH + 192;
constexpr int LDS_FLOATS = OFF_B2 + 16;
}

__device__ __forceinline__ float bcastf(float v, int l) {
  return __int_as_float(__builtin_amdgcn_readlane(__float_as_int(v), l));
}

__global__ __launch_bounds__(512, 1)
void drqn_fused(const float* __restrict__ obs, const int* __restrict__ agent,
                const float* __restrict__ W1, const float* __restrict__ b1,
                const float* __restrict__ Wih, const float* __restrict__ Whh,
                const float* __restrict__ bih, const float* __restrict__ bhh,
                const float* __restrict__ W2, const float* __restrict__ b2,
                float* __restrict__ out) {
  using namespace fb;
  extern __shared__ float lds[];
  float* W1s = lds + OFF_W1; float* Wihs = lds + OFF_WIH;
  float* Whhs = lds + OFF_WHH; float* W2s = lds + OFF_W2;
  float* b1s = lds + OFF_B1; float* bihs = lds + OFF_BIH;
  float* bhhs = lds + OFF_BHH; float* b2s = lds + OFF_B2;
  const int tid = threadIdx.x;
  for (int i = tid; i < 64 * 136; i += 512) { int r = i / 136, c = i - r * 136; W1s[r * kW1Pitch + c] = W1[i]; }
  for (int i = tid; i < 192 * 64; i += 512) { int r = i >> 6, c = i & 63; Wihs[r * kHPitch + c] = Wih[i]; }
  for (int i = tid; i < 192 * 64; i += 512) { int r = i >> 6, c = i & 63; Whhs[r * kHPitch + c] = Whh[i]; }
  for (int i = tid; i < 16 * 64; i += 512) { int r = i >> 6, c = i & 63; W2s[r * kHPitch + c] = W2[i]; }
  if (tid < 64) b1s[tid] = b1[tid];
  if (tid < 192) bihs[tid] = bih[tid];
  if (tid < 192) bhhs[tid] = bhh[tid];
  if (tid < 16) b2s[tid] = b2[tid];
  __syncthreads();
  const int wave = tid >> 6, lane = tid & 63;
  const int s = blockIdx.x * 8 + wave;
  const int b = s >> 3, n = s & 7;
  const int acol = 128 + agent[n];
  const float* obase = obs + (((size_t)b * kT) * kN + n) * kObs;
  const size_t qbase = (((size_t)b * kT) * kN + n) * kOut;
  const size_t mbase = ((size_t)b * kT) * kN + n;
  float* outq = out;
  float* outmv = out + (size_t)kB * kT * kN * kOut;
  float* outma = outmv + (size_t)kB * kT * kN;
  float h = 0.f;
  float xa = obase[lane], xb = obase[64 + lane];
  #pragma unroll 1
  for (int t = 0; t < kT; ++t) {
    float xan = 0.f, xbn = 0.f;
    if (t + 1 < kT) { const float* p = obase + (size_t)(t + 1) * kN * kObs; xan = p[lane]; xbn = p[64 + lane]; }
    float acc = b1s[lane] + W1s[lane * kW1Pitch + acol];
    #pragma unroll
    for (int k = 0; k < 64; ++k) acc += W1s[lane * kW1Pitch + k] * bcastf(xa, k);
    #pragma unroll
    for (int k = 0; k < 64; ++k) acc += W1s[lane * kW1Pitch + 64 + k] * bcastf(xb, k);
    float a = fmaxf(acc, 0.f);
    float air = bihs[lane], aiz = bihs[64 + lane], ain = bihs[128 + lane];
    #pragma unroll
    for (int k = 0; k < 64; ++k) {
      float sa = bcastf(a, k);
      air += Wihs[lane * kHPitch + k] * sa;
      aiz += Wihs[(64 + lane) * kHPitch + k] * sa;
      ain += Wihs[(128 + lane) * kHPitch + k] * sa;
    }
    float ghr = bhhs[lane], ghz = bhhs[64 + lane], ghn = bhhs[128 + lane];
    #pragma unroll
    for (int k = 0; k < 64; ++k) {
      float sh = bcastf(h, k);
      ghr += Whhs[lane * kHPitch + k] * sh;
      ghz += Whhs[(64 + lane) * kHPitch + k] * sh;
      ghn += Whhs[(128 + lane) * kHPitch + k] * sh;
    }
    float rg = 1.f / (1.f + expf(-(air + ghr)));
    float zg = 1.f / (1.f + expf(-(aiz + ghz)));
    float ng = tanhf(ain + rg * ghn);
    h = (1.f - zg) * ng + zg * h;
    const int m = lane & 15;
    float q = b2s[m];
    #pragma unroll
    for (int k = 0; k < 64; ++k) q += W2s[m * kHPitch + k] * bcastf(h, k);
    if (lane < 16) outq[qbase + (size_t)t * kN * kOut + m] = q;
    float bv = q; int bi = m;
    #pragma unroll
    for (int d = 1; d < 16; d <<= 1) {
      float ov = __shfl_xor(bv, d, 16);
      int oi = __shfl_xor(bi, d, 16);
      if (ov > bv || (ov == bv && oi < bi)) { bv = ov; bi = oi; }
    }
    if (lane == 0) { outmv[mbase + (size_t)t * kN] = bv; outma[mbase + (size_t)t * kN] = (float)bi; }
    xa = xan; xb = xbn;
  }
}

extern "C" void kernel_launch(void* const* d_in, const int* in_sizes, int n_in,
                              void* d_out, int out_size, void* d_ws, size_t ws_size,
                              hipStream_t stream) {
  const float* obs  = (const float*)d_in[0];
  const int* agent  = (const int*)d_in[1];
  const float* W1   = (const float*)d_in[2];
  const float* b1   = (const float*)d_in[3];
  const float* Wih  = (const float*)d_in[4];
  const float* Whh  = (const float*)d_in[5];
  const float* bih  = (const float*)d_in[6];
  const float* bhh  = (const float*)d_in[7];
  const float* W2   = (const float*)d_in[8];
  const float* b2   = (const float*)d_in[9];
  float* out = (float*)d_out;

  if (ws_size >= kABytes + kGiBytes) {
    float* a_buf  = (float*)d_ws;
    float* gi_buf = (float*)((char*)d_ws + kABytes);
    fc1_k<<<dim3(2048), dim3(256), 0, stream>>>(obs, agent, W1, b1, a_buf);
    gi_k<<<dim3(512), dim3(256), 0, stream>>>(a_buf, Wih, bih, gi_buf);
    gru4_k<<<dim3(1024), dim3(64), 0, stream>>>(gi_buf, Whh, bhh, W2, b2, out);
  } else {
    (void)hipFuncSetAttribute((const void*)drqn_fused,
                              hipFuncAttributeMaxDynamicSharedMemorySize,
                              fb::LDS_FLOATS * 4);
    drqn_fused<<<dim3(256), dim3(512), fb::LDS_FLOATS * 4, stream>>>(
        obs, agent, W1, b1, Wih, Whh, bih, bhh, W2, b2, out);
  }
}